// Round 5
// baseline (643.975 us; speedup 1.0000x reference)
//
#include <hip/hip_runtime.h>
#include <cstdint>
#include <cstddef>

// QRNN fused pipeline for MI355X (gfx950).
// B=32, S=2048, D_in=512, D_model=1024, D_mlp=1024, n_cls=128.
//
// ws layout (bytes): U bf16 [2048][1024] @0 (4MB) | Fagg @4MB | Zagg @6MB |
//   h @8MB | q0 @8MB+256K | q1 @8MB+512K | zero page @12MB (4KB) | xb bf16 @16MB (64MB)
//
// qrnn_main4 (round 5): back to the 3-blocks/CU shape (128x128 tile, 256 thr,
// 4 waves, acc[4][4] = 64 AGPR) which gave the m114-style cross-block overlap
// the 8-wave/1-block-per-CU structure lacked (rounds 1-4 plateaued at ~30%
// MfmaUtil with every pipe idling in barrier lockstep). Keeps this session's
// verified wins:
//  - global_load_lds staging (no ds_writes, no staging VGPRs -> kills the old
//    kernel's 61% VALUBusy staging cost)
//  - ring-3 LDS slots (3 x 16KB = 48KB -> 3 blocks/CU)
//  - structural xprev: ksteps 0..15 = x[t] * U[k<512] (W), 16..31 = x[t-1] *
//    U[k>=512] (V); t=-1 reads the zero page
//  - source-pre-swizzled conflict-free LDS (linear gload dest, rule #21)
//  - one counted vmcnt(4) + one barrier per kstep (loads span 2 ksteps)
//  - XCD-chunked block swizzle (same-panel blocks on one XCD; FETCH 541->165MB)
// Epilogue/head: old verified 16-chunk layout, reused verbatim.

typedef __attribute__((ext_vector_type(8))) short short8;
typedef __attribute__((ext_vector_type(4))) float f32x4;

#define ZERO_OFF_E 6291456u    // 12MB / 2 (bf16 elements)
#define XB_OFF_E   8388608u    // 16MB / 2
#define U_LDS_BASE 8256        // (fallback kernel) A stage = 129 rows * 64B

__device__ __forceinline__ unsigned short f2bf(float f) {
  unsigned int u = __float_as_uint(f);
  u += 0x7fffu + ((u >> 16) & 1u);
  return (unsigned short)(u >> 16);
}

__device__ __forceinline__ unsigned stage_addr(int r, int c) {
  return (unsigned)(r * 64 + (((c + r + (r >> 2)) & 3) << 4));
}

__device__ __forceinline__ float sigmoidf_fast(float x) {
  return 1.f / (1.f + __expf(-x));
}
__device__ __forceinline__ float tanhf_fast(float x) {
  float a = fabsf(x);
  float e = __expf(-2.f * a);
  float t = (1.f - e) / (1.f + e);
  return copysignf(t, x);
}

// async 16B global->LDS. LDS dest must be wave-uniform base; lane lands at
// base + lane*16.
__device__ __forceinline__ void gload_lds16(const void* g, const char* lds) {
  __builtin_amdgcn_global_load_lds(
      (const __attribute__((address_space(1))) void*)(uintptr_t)g,
      (__attribute__((address_space(3))) void*)(uint32_t)(uintptr_t)lds, 16, 0, 0);
}

// ---------------- prologue ----------------
// grid 8833: [0,8192) pack_x (4 float4/thread); [8192,8704) pack_u; [8704,8832) init; 8832 zpg
__global__ void prologue_kernel(const float* __restrict__ x, const float* __restrict__ W,
                                const float* __restrict__ V,
                                const float* __restrict__ b0, const float* __restrict__ b1,
                                const float* __restrict__ b2,
                                unsigned short* __restrict__ xb, unsigned short* __restrict__ U,
                                float* __restrict__ q0, float* __restrict__ q1,
                                float* __restrict__ out, uint4* __restrict__ zpg) {
  __shared__ float T[64 * 65];
  const int bx = blockIdx.x;
  if (bx < 8192) {
    int base = bx * 1024 + threadIdx.x;
#pragma unroll
    for (int i = 0; i < 4; ++i) {
      int gid = base + i * 256;
      float4 v = ((const float4*)x)[gid];
      ushort4 o;
      o.x = f2bf(v.x); o.y = f2bf(v.y); o.z = f2bf(v.z); o.w = f2bf(v.w);
      ((ushort4*)xb)[gid] = o;
    }
  } else if (bx < 8704) {
    const int u = bx - 8192;
    const int j0 = (u & 31) * 64;
    const int k0 = (u >> 5) * 64;
    const int jl = threadIdx.x & 63;
    const int q  = threadIdx.x >> 6;
    const float* src = (k0 < 512) ? (W + (size_t)k0 * 3072) : (V + (size_t)(k0 - 512) * 3072);
#pragma unroll 4
    for (int i = 0; i < 16; ++i) {
      int kl = q * 16 + i;
      T[kl * 65 + jl] = src[(size_t)kl * 3072 + j0 + jl];
    }
    __syncthreads();
    const int kl = threadIdx.x & 63;
#pragma unroll 4
    for (int i = 0; i < 16; ++i) {
      int jj = q * 16 + i;
      U[(size_t)(j0 + jj) * 1024 + k0 + kl] = f2bf(T[kl * 65 + jj]);
    }
  } else if (bx < 8832) {
    int gid = (bx - 8704) * 256 + threadIdx.x;   // 32768
    q0[gid] = b0[gid & 1023];
    q1[gid] = b1[gid & 1023];
    if (gid < 4096) out[gid] = b2[gid & 127];
  } else {
    zpg[threadIdx.x] = make_uint4(0u, 0u, 0u, 0u);   // 4 KB zeros
  }
}

// ---------------- main (bf16 path): 128^2 4-wave, 3 blocks/CU, gload_lds ----------------
// grid 8192 (1D, XCD-chunked), block 256 (waves: wm=wid>>1 x wn=wid&1)
// per wave: 64 t-rows x 64 cols -> acc[4][4] f32x4 (64 AGPR).
__global__ __launch_bounds__(256, 3) void qrnn_main4(
    const unsigned short* __restrict__ wsb, const float* __restrict__ Vb,
    float* __restrict__ Fagg, float* __restrict__ Zagg) {
  __shared__ __align__(16) char smem[49152];   // 3 ring slots x 16KB

  // XCD-chunked swizzle: nwg=8192, %8==0 -> bijective. The 16 dt-blocks that
  // share a (b,cj) A-panel are consecutive in orig -> same XCD.
  const int bid  = blockIdx.x;
  const int orig = (bid & 7) * 1024 + (bid >> 3);
  const int dt = orig & 15;
  const int cj = (orig >> 4) & 15;
  const int b  = orig >> 8;

  const int tid = threadIdx.x;
  const int lane = tid & 63;
  const int wid  = tid >> 6;
  const int wm = wid >> 1, wn = wid & 1;
  const int l15 = lane & 15, lc = lane >> 4;
  const int s0 = cj * 128;

  f32x4 acc[4][4];
#pragma unroll
  for (int i = 0; i < 4; ++i)
#pragma unroll
    for (int j = 0; j < 4; ++j) acc[i][j] = f32x4{0.f, 0.f, 0.f, 0.f};

  // ---- per-lane staging source offsets (bf16 elements rel. wsb) ----
  // wave w stages A rows [w*32,w*32+32) and B rows same; 2 instr each (16 rows).
  // lane l -> row_g = base + (l>>2), phys 16B-slot p = l&3; source uses logical
  // slot q = p ^ ((row_g>>1)&3) (involution) so swizzled reads see linear data.
  unsigned eAx[2], eAp[2], eB[2];
#pragma unroll
  for (int i = 0; i < 2; ++i) {
    int row_g = wid * 32 + i * 16 + (lane >> 2);          // 0..127
    int q = (lane & 3) ^ ((row_g >> 1) & 3);
    int tx = s0 + row_g;                                  // ksteps 0..15: x[t]
    eAx[i] = XB_OFF_E + (unsigned)(b * 2048 + tx) * 512u + (unsigned)(q * 8);
    int tp = s0 - 1 + row_g;                              // ksteps 16..31: x[t-1]
    eAp[i] = (tp < 0) ? (ZERO_OFF_E + (unsigned)(q * 8))
                      : (XB_OFF_E + (unsigned)(b * 2048 + tp) * 512u + (unsigned)(q * 8));
    // B rows: col 0..63 -> f-gate U row dt*64+col; 64..127 -> z-gate 1024+dt*64+(col-64)
    int jj = (row_g < 64) ? (dt * 64 + row_g) : (1024 + dt * 64 + (row_g - 64));
    eB[i] = (unsigned)jj * 1024u + (unsigned)(q * 8);
  }

  // ---- fragment read offsets (swizzle lc ^ ((l15>>1)&3); row-base mult of 16) ----
  const unsigned swz = (unsigned)((lc ^ ((l15 >> 1) & 3)) << 4);
  const unsigned oA = (unsigned)((wm * 64 + l15) * 64) + swz;            // A rows
  const unsigned oB = 8192u + (unsigned)((wn * 64 + l15) * 64) + swz;    // B rows

  auto stage = [&](int kt, int slot) {
    const unsigned sbase = (unsigned)(slot * 16384);
    const bool xp = (kt < 16);
    const unsigned kaddA = xp ? (unsigned)(kt * 32) : (unsigned)((kt - 16) * 32);
    const unsigned kaddB = (unsigned)(kt * 32);
#pragma unroll
    for (int i = 0; i < 2; ++i) {
      unsigned da = (unsigned)__builtin_amdgcn_readfirstlane(
          (int)(sbase + (unsigned)(wid * 2048 + i * 1024)));
      gload_lds16(wsb + ((xp ? eAx[i] : eAp[i]) + kaddA), smem + da);
    }
#pragma unroll
    for (int i = 0; i < 2; ++i) {
      unsigned db = (unsigned)__builtin_amdgcn_readfirstlane(
          (int)(sbase + 8192u + (unsigned)(wid * 2048 + i * 1024)));
      gload_lds16(wsb + (eB[i] + kaddB), smem + db);
    }
  };

  // ---- prologue: slots 0,1 in flight (8 gloads); wait slot0; barrier ----
  stage(0, 0);
  stage(1, 1);
  asm volatile("s_waitcnt vmcnt(4)" ::: "memory");
  __builtin_amdgcn_s_barrier();

  // One kstep: [vmcnt; barrier; stage(kt+2); 8 ds_read; 16 MFMA].
  // Ring-3 WAW safe: slot (kt+2)%3's readers (kstep kt-1) completed their
  // ds_reads before their MFMAs, which precede this barrier; gloads are
  // issued after it. vmcnt(4)+barrier => slot kt landed for ALL waves.
#define KSTEP(KT, CUR, STG, LAST)                                                    \
  {                                                                                  \
    const int kt = (KT);                                                             \
    if (LAST) asm volatile("s_waitcnt vmcnt(0)" ::: "memory");                       \
    else      asm volatile("s_waitcnt vmcnt(4)" ::: "memory");                       \
    __builtin_amdgcn_s_barrier();                                                    \
    if (kt < 30) stage(kt + 2, (STG));                                               \
    const char* buf = smem + (CUR) * 16384;                                          \
    short8 afr[4], bfr[4];                                                           \
    _Pragma("unroll")                                                                \
    for (int mt = 0; mt < 4; ++mt) afr[mt] = *(const short8*)(buf + oA + mt * 1024); \
    _Pragma("unroll")                                                                \
    for (int nt = 0; nt < 4; ++nt) bfr[nt] = *(const short8*)(buf + oB + nt * 1024); \
    _Pragma("unroll")                                                                \
    for (int mt = 0; mt < 4; ++mt)                                                   \
      _Pragma("unroll")                                                              \
      for (int nt = 0; nt < 4; ++nt)                                                 \
        acc[mt][nt] =                                                                \
            __builtin_amdgcn_mfma_f32_16x16x32_bf16(afr[mt], bfr[nt], acc[mt][nt], 0, 0, 0); \
  }

#pragma unroll 1
  for (int k3 = 0; k3 < 30; k3 += 3) {
    KSTEP(k3,     0, 2, false);
    KSTEP(k3 + 1, 1, 0, false);
    KSTEP(k3 + 2, 2, 1, false);
  }
  KSTEP(30, 0, 0, false);
  KSTEP(31, 1, 0, true);
#undef KSTEP

  // ---- fused activations + scan (old verified epilogue; 2 phases x 64 t) ----
  float* fA   = (float*)smem;            // [64][68]
  float* tzA  = (float*)(smem + 17408);  // [64][68]
  float* segF = (float*)(smem + 34816);  // [4][64]
  float* segZ = (float*)(smem + 35840);  // [4][64]

  const int d = tid & 63;
  float vb[4];
#pragma unroll
  for (int nt = 0; nt < 4; ++nt)
    vb[nt] = Vb[wn * 1024 + dt * 64 + nt * 16 + l15];

  float F_run = 1.f, Z_run = 0.f;

  for (int ph = 0; ph < 2; ++ph) {
    __syncthreads();
    if (wm == ph) {
      float* dst = (wn == 0) ? fA : tzA;
#pragma unroll
      for (int mt = 0; mt < 4; ++mt)
#pragma unroll
        for (int nt = 0; nt < 4; ++nt)
#pragma unroll
          for (int rg = 0; rg < 4; ++rg) {
            int t = mt * 16 + (lc << 2) + rg;   // phase-local 0..63
            int c = nt * 16 + l15;
            float v = acc[mt][nt][rg] + vb[nt];
            v = (wn == 0) ? sigmoidf_fast(v) : tanhf_fast(v);
            dst[t * 68 + c] = v;
          }
    }
    __syncthreads();
    {
      int seg = tid >> 6;
      float F = 1.f, Z = 0.f;
#pragma unroll 4
      for (int i = 0; i < 16; ++i) {
        int t = seg * 16 + i;
        float f  = fA[t * 68 + d];
        float tz = tzA[t * 68 + d];
        float z = (1.f - f) * tz;
        Z = f * Z + z;
        F *= f;
      }
      segF[seg * 64 + d] = F;
      segZ[seg * 64 + d] = Z;
    }
    __syncthreads();
    if (tid < 64) {
#pragma unroll
      for (int sgi = 0; sgi < 4; ++sgi) {
        float Fs = segF[sgi * 64 + tid], Zs = segZ[sgi * 64 + tid];
        Z_run = Fs * Z_run + Zs;
        F_run *= Fs;
      }
    }
  }
  if (tid < 64) {
    size_t o = (((size_t)b * 16 + cj) << 10) + dt * 64 + tid;
    Fagg[o] = F_run;
    Zagg[o] = Z_run;
  }
}

// ---------------- fallback (f32 path, 16-chunk layout) — previous verified kernel ----------------
template <bool USE_BF>
__global__ __launch_bounds__(256, 3) void qrnn_main(
    const unsigned short* __restrict__ wsb, const float* __restrict__ xf,
    const float* __restrict__ Vb,
    float* __restrict__ Fagg, float* __restrict__ Zagg) {
  __shared__ __align__(16) char smem[36864];

  const int dt = blockIdx.x;
  const int cj = blockIdx.y;
  const int b  = blockIdx.z;
  const int tid = threadIdx.x;
  const int lane = tid & 63;
  const int wid  = tid >> 6;
  const int wm = wid >> 1, wn = wid & 1;
  const int s0 = cj * 128;
  const int l15 = lane & 15, lc = lane >> 4;

  f32x4 acc[4][4];
#pragma unroll
  for (int i = 0; i < 4; ++i)
#pragma unroll
    for (int j = 0; j < 4; ++j) acc[i][j] = f32x4{0.f, 0.f, 0.f, 0.f};

  unsigned voffA[2];
  size_t offAF[2]; int zAF[2];
#pragma unroll
  for (int p = 0; p < 2; ++p) {
    int cw = tid + p * 256;
    int r = cw >> 2, c = cw & 3;
    int sg = s0 - 1 + r;
    voffA[p] = (sg < 0) ? (ZERO_OFF_E + (unsigned)(c * 8))
                        : (XB_OFF_E + (unsigned)(b * 2048 + sg) * 512u + (unsigned)(c * 8));
    zAF[p] = (sg < 0);
    offAF[p] = ((size_t)(b * 2048 + (sg < 0 ? 0 : sg)) << 9) + c * 8;
  }
  unsigned voffA3 = XB_OFF_E + (unsigned)(b * 2048 + s0 + 127) * 512u + (unsigned)((tid & 3) * 8);
  size_t offAF3 = ((size_t)(b * 2048 + s0 + 127) << 9) + (tid & 3) * 8;

  unsigned voffU[4];
#pragma unroll
  for (int k = 0; k < 4; ++k) {
    int uw = tid + k * 256;
    int r = uw >> 2, c = uw & 3;
    int col = r & 127, half = r >> 7;
    int j = (col < 64) ? (dt * 64 + col) : (1024 + dt * 64 + (col - 64));
    voffU[k] = (unsigned)(j * 1024 + half * 512 + c * 8);
  }

  unsigned wA[2], wU[4];
#pragma unroll
  for (int p = 0; p < 2; ++p) {
    int cw = tid + p * 256;
    wA[p] = stage_addr(cw >> 2, cw & 3);
  }
  const unsigned wA3 = stage_addr(128, tid & 3);
#pragma unroll
  for (int k = 0; k < 4; ++k) {
    int uw = tid + k * 256;
    wU[k] = U_LDS_BASE + stage_addr(uw >> 2, uw & 3);
  }

  unsigned roA[2][4], roU[2][4];
#pragma unroll
  for (int h2 = 0; h2 < 2; ++h2) {
#pragma unroll
    for (int mt = 0; mt < 4; ++mt) {
      int rr = wm * 64 + l15 + mt * 16 + 1 - h2;
      roA[h2][mt] = stage_addr(rr, lc);
    }
#pragma unroll
    for (int nt = 0; nt < 4; ++nt) {
      int rrU = h2 * 128 + wn * 64 + l15 + nt * 16;
      roU[h2][nt] = U_LDS_BASE + stage_addr(rrU, lc);
    }
  }

  uint4 pA0, pA1, pA3, pU0, pU1, pU2, pU3;

  auto load_stage = [&](int s) {
    const unsigned short* cur = wsb + s * 32;
    if constexpr (USE_BF) {
      pA0 = *(const uint4*)(cur + voffA[0]);
      pA1 = *(const uint4*)(cur + voffA[1]);
      if (tid < 4) pA3 = *(const uint4*)(cur + voffA3);
    } else {
      const float* curf = xf + s * 32;
#pragma unroll
      for (int p = 0; p < 2; ++p) {
        uint4 v = make_uint4(0u, 0u, 0u, 0u);
        if (!zAF[p]) {
          float4 a0 = *(const float4*)(curf + offAF[p]);
          float4 a1 = *(const float4*)(curf + offAF[p] + 4);
          v.x = (unsigned)f2bf(a0.x) | ((unsigned)f2bf(a0.y) << 16);
          v.y = (unsigned)f2bf(a0.z) | ((unsigned)f2bf(a0.w) << 16);
          v.z = (unsigned)f2bf(a1.x) | ((unsigned)f2bf(a1.y) << 16);
          v.w = (unsigned)f2bf(a1.z) | ((unsigned)f2bf(a1.w) << 16);
        }
        if (p == 0) pA0 = v; else pA1 = v;
      }
      if (tid < 4) {
        float4 a0 = *(const float4*)(curf + offAF3);
        float4 a1 = *(const float4*)(curf + offAF3 + 4);
        pA3.x = (unsigned)f2bf(a0.x) | ((unsigned)f2bf(a0.y) << 16);
        pA3.y = (unsigned)f2bf(a0.z) | ((unsigned)f2bf(a0.w) << 16);
        pA3.z = (unsigned)f2bf(a1.x) | ((unsigned)f2bf(a1.y) << 16);
        pA3.w = (unsigned)f2bf(a1.z) | ((unsigned)f2bf(a1.w) << 16);
      }
    }
    pU0 = *(const uint4*)(cur + voffU[0]);
    pU1 = *(const uint4*)(cur + voffU[1]);
    pU2 = *(const uint4*)(cur + voffU[2]);
    pU3 = *(const uint4*)(cur + voffU[3]);
  };

  load_stage(0);

#pragma unroll 1
  for (int s = 0; s < 16; ++s) {
    __syncthreads();
    *(uint4*)(smem + wA[0]) = pA0;
    *(uint4*)(smem + wA[1]) = pA1;
    if (tid < 4) *(uint4*)(smem + wA3) = pA3;
    *(uint4*)(smem + wU[0]) = pU0;
    *(uint4*)(smem + wU[1]) = pU1;
    *(uint4*)(smem + wU[2]) = pU2;
    *(uint4*)(smem + wU[3]) = pU3;
    __syncthreads();
    if (s < 15) load_stage(s + 1);
#pragma unroll
    for (int h2 = 0; h2 < 2; ++h2) {
      short8 bfr[4];
#pragma unroll
      for (int nt = 0; nt < 4; ++nt)
        bfr[nt] = *(const short8*)(smem + roU[h2][nt]);
#pragma unroll
      for (int mt = 0; mt < 4; ++mt) {
        short8 afr = *(const short8*)(smem + roA[h2][mt]);
#pragma unroll
        for (int nt = 0; nt < 4; ++nt)
          acc[mt][nt] = __builtin_amdgcn_mfma_f32_16x16x32_bf16(afr, bfr[nt], acc[mt][nt], 0, 0, 0);
      }
    }
  }

  float* fA   = (float*)smem;
  float* tzA  = (float*)(smem + 17408);
  float* segF = (float*)(smem + 34816);
  float* segZ = (float*)(smem + 35840);

  const int d = tid & 63;
  float vb[4];
#pragma unroll
  for (int nt = 0; nt < 4; ++nt)
    vb[nt] = Vb[wn * 1024 + dt * 64 + nt * 16 + l15];

  float F_run = 1.f, Z_run = 0.f;

  for (int ph = 0; ph < 2; ++ph) {
    __syncthreads();
    if (wm == ph) {
      float* dst = (wn == 0) ? fA : tzA;
#pragma unroll
      for (int mt = 0; mt < 4; ++mt)
#pragma unroll
        for (int nt = 0; nt < 4; ++nt)
#pragma unroll
          for (int rg = 0; rg < 4; ++rg) {
            int t = mt * 16 + ((lane >> 4) << 2) + rg;
            int c = nt * 16 + l15;
            float v = acc[mt][nt][rg] + vb[nt];
            v = (wn == 0) ? sigmoidf_fast(v) : tanhf_fast(v);
            dst[t * 68 + c] = v;
          }
    }
    __syncthreads();
    {
      int seg = tid >> 6;
      float F = 1.f, Z = 0.f;
#pragma unroll 4
      for (int i = 0; i < 16; ++i) {
        int t = seg * 16 + i;
        float f  = fA[t * 68 + d];
        float tz = tzA[t * 68 + d];
        float z = (1.f - f) * tz;
        Z = f * Z + z;
        F *= f;
      }
      segF[seg * 64 + d] = F;
      segZ[seg * 64 + d] = Z;
    }
    __syncthreads();
    if (tid < 64) {
#pragma unroll
      for (int sgi = 0; sgi < 4; ++sgi) {
        float Fs = segF[sgi * 64 + tid], Zs = segZ[sgi * 64 + tid];
        Z_run = Fs * Z_run + Zs;
        F_run *= Fs;
      }
    }
  }
  if (tid < 64) {
    size_t o = (((size_t)b * 16 + cj) << 10) + dt * 64 + tid;
    Fagg[o] = F_run;
    Zagg[o] = Z_run;
  }
}

// ---------------- head: K-split o-gate + nch-chunk combine ----------------
// grid (16 dtile, 32 b), block 256 = 64 d x 4 k-segments
__global__ void head_kernel(const float* __restrict__ x, const float* __restrict__ W,
                            const float* __restrict__ V, const float* __restrict__ Vb,
                            const float* __restrict__ Fagg, const float* __restrict__ Zagg,
                            float* __restrict__ h, int nch) {
  __shared__ float red[4][64];
  const int dl = threadIdx.x & 63;
  const int w  = threadIdx.x >> 6;
  const int d = blockIdx.x * 64 + dl;
  const int b = blockIdx.y;

  const float* xl = x + ((size_t)b * 2048 + 2047) * 512;
  const float* xp = xl - 512;
  const float* Wc = W + 2048 + d;
  const float* Vc = V + 2048 + d;
  float po = 0.f;
  const int k0 = w * 128;
#pragma unroll 8
  for (int k = k0; k < k0 + 128; ++k) {
    po += xl[k] * Wc[(size_t)k * 3072];
    po += xp[k] * Vc[(size_t)k * 3072];
  }
  red[w][dl] = po;
  __syncthreads();
  if (w == 0) {
    po = red[0][dl] + red[1][dl] + red[2][dl] + red[3][dl] + Vb[2048 + d];
    float c = 0.f;
    for (int j = 0; j < nch; ++j) {
      size_t o = (((size_t)b * nch + j) << 10) + d;
      c = Fagg[o] * c + Zagg[o];
    }
    h[((size_t)b << 10) + d] = c * sigmoidf_fast(po);
  }
}

// ---------------- MLP: K-split atomic GEMV (ReLU on input) ----------------
// grid (N/64, B, 4 ksplit), block 256 = 64 n x 4 waves
__global__ void mlp_atomic_kernel(const float* __restrict__ in, const float* __restrict__ Wt,
                                  float* __restrict__ out, int K, int N, int relu_in) {
  __shared__ float red[4][64];
  const int nl = threadIdx.x & 63;
  const int w  = threadIdx.x >> 6;
  const int n = blockIdx.x * 64 + nl;
  const int b = blockIdx.y;
  const int k0 = blockIdx.z * (K >> 2) + w * (K >> 4);
  const float* row = in + (size_t)b * K;
  const float* Wc = Wt + n;
  float s = 0.f;
#pragma unroll 8
  for (int k = k0; k < k0 + (K >> 4); ++k) {
    float v = row[k];
    if (relu_in) v = fmaxf(v, 0.f);
    s += v * Wc[(size_t)k * N];
  }
  red[w][nl] = s;
  __syncthreads();
  if (w == 0) {
    s = red[0][nl] + red[1][nl] + red[2][nl] + red[3][nl];
    atomicAdd(&out[(size_t)b * N + n], s);
  }
}

extern "C" void kernel_launch(void* const* d_in, const int* in_sizes, int n_in,
                              void* d_out, int out_size, void* d_ws, size_t ws_size,
                              hipStream_t stream) {
  const float* x  = (const float*)d_in[0];
  const float* W  = (const float*)d_in[1];
  const float* V  = (const float*)d_in[2];
  const float* Vb = (const float*)d_in[3];
  const float* W0 = (const float*)d_in[4];
  const float* b0 = (const float*)d_in[5];
  const float* W1 = (const float*)d_in[6];
  const float* b1 = (const float*)d_in[7];
  const float* W2 = (const float*)d_in[8];
  const float* b2 = (const float*)d_in[9];

  char* ws = (char*)d_ws;
  unsigned short* U = (unsigned short*)(ws);                              // 4 MiB
  float* Fagg = (float*)(ws + (size_t)4 * 1024 * 1024);                   // 2 MiB
  float* Zagg = (float*)(ws + (size_t)6 * 1024 * 1024);                   // 2 MiB
  float* h    = (float*)(ws + (size_t)8 * 1024 * 1024);                   // 128 KiB
  float* q0   = (float*)(ws + (size_t)8 * 1024 * 1024 + 256 * 1024);
  float* q1   = (float*)(ws + (size_t)8 * 1024 * 1024 + 512 * 1024);
  uint4* zpg  = (uint4*)(ws + (size_t)12 * 1024 * 1024);                  // 4 KiB zeros
  unsigned short* xb = (unsigned short*)(ws + (size_t)16 * 1024 * 1024);  // 64 MiB

  const size_t need_bf = (size_t)16 * 1024 * 1024 + (size_t)67108864;
  int use_bf = (ws_size >= need_bf) ? 1 : 0;   // constant across calls -> graph-safe

  prologue_kernel<<<8833, 256, 0, stream>>>(x, W, V, b0, b1, b2, xb, U, q0, q1,
                                            (float*)d_out, zpg);
  if (use_bf) {
    qrnn_main4<<<8192, 256, 0, stream>>>((const unsigned short*)ws, Vb, Fagg, Zagg);
  } else {
    qrnn_main<false><<<dim3(16, 16, 32), 256, 0, stream>>>((const unsigned short*)ws, x,
                                                           Vb, Fagg, Zagg);
  }
  head_kernel<<<dim3(16, 32), 256, 0, stream>>>(x, W, V, Vb, Fagg, Zagg, h, 16);
  mlp_atomic_kernel<<<dim3(16, 32, 4), 256, 0, stream>>>(h, W0, q0, 1024, 1024, 0);
  mlp_atomic_kernel<<<dim3(16, 32, 4), 256, 0, stream>>>(q0, W1, q1, 1024, 1024, 1);
  mlp_atomic_kernel<<<dim3(2, 32, 4), 256, 0, stream>>>(q1, W2, (float*)d_out, 1024, 128, 1);
}

// Round 6
// 632.475 us; speedup vs baseline: 1.0182x; 1.0182x over previous
//
#include <hip/hip_runtime.h>
#include <cstdint>
#include <cstddef>

// QRNN fused pipeline for MI355X (gfx950).
// B=32, S=2048, D_in=512, D_model=1024, D_mlp=1024, n_cls=128.
//
// ws layout (bytes): U bf16 [2048][1024] @0 (4MB) | Fagg @4MB | Zagg @6MB |
//   h @8MB | q0 @8MB+256K | q1 @8MB+512K | zero page @12MB (4KB) | xb bf16 @16MB (64MB)
//
// qrnn_main4 (round 6): 128x128 tile, 256 thr, 4 waves, acc[4][4] (64 AGPR),
// RE-BUDGETED FOR 4 BLOCKS/CU (the round-5 post-mortem lever):
//  - ring-2 LDS (2 x 16KB) + 36864B total (epilogue overlay) -> LDS allows 4
//  - __launch_bounds__(256,4): unified regs <= 128 (64 acc + <=64 VGPR) ->
//    4 waves/SIMD (m69 rule: r5's 136 regs was 8 over the 128 boundary)
//  - per kstep: vmcnt(0); barrier; stage(kt+1, buf^1); 8 ds_read; setprio(1);
//    16 MFMA; setprio(0). The drain is hidden by the 3 OTHER resident blocks
//    (m114 cross-block overlap - r0's 37.6% MfmaUtil came from this).
// Verified pieces kept from r5 (PASSED): gload_lds staging, pre-swizzled
// conflict-free LDS (rule #21), structural xprev (ksteps 0..15 x[t]*W-half,
// 16..31 x[t-1]*V-half, zero page at t=-1), (b,cj)-chunked XCD swizzle,
// 16-chunk scan epilogue + head.

typedef __attribute__((ext_vector_type(8))) short short8;
typedef __attribute__((ext_vector_type(4))) float f32x4;

#define ZERO_OFF_E 6291456u    // 12MB / 2 (bf16 elements)
#define XB_OFF_E   8388608u    // 16MB / 2
#define U_LDS_BASE 8256        // (fallback kernel) A stage = 129 rows * 64B

__device__ __forceinline__ unsigned short f2bf(float f) {
  unsigned int u = __float_as_uint(f);
  u += 0x7fffu + ((u >> 16) & 1u);
  return (unsigned short)(u >> 16);
}

__device__ __forceinline__ unsigned stage_addr(int r, int c) {
  return (unsigned)(r * 64 + (((c + r + (r >> 2)) & 3) << 4));
}

__device__ __forceinline__ float sigmoidf_fast(float x) {
  return 1.f / (1.f + __expf(-x));
}
__device__ __forceinline__ float tanhf_fast(float x) {
  float a = fabsf(x);
  float e = __expf(-2.f * a);
  float t = (1.f - e) / (1.f + e);
  return copysignf(t, x);
}

// async 16B global->LDS. LDS dest must be wave-uniform base; lane lands at
// base + lane*16.
__device__ __forceinline__ void gload_lds16(const void* g, const char* lds) {
  __builtin_amdgcn_global_load_lds(
      (const __attribute__((address_space(1))) void*)(uintptr_t)g,
      (__attribute__((address_space(3))) void*)(uint32_t)(uintptr_t)lds, 16, 0, 0);
}

// ---------------- prologue ----------------
// grid 8833: [0,8192) pack_x (4 float4/thread); [8192,8704) pack_u; [8704,8832) init; 8832 zpg
__global__ void prologue_kernel(const float* __restrict__ x, const float* __restrict__ W,
                                const float* __restrict__ V,
                                const float* __restrict__ b0, const float* __restrict__ b1,
                                const float* __restrict__ b2,
                                unsigned short* __restrict__ xb, unsigned short* __restrict__ U,
                                float* __restrict__ q0, float* __restrict__ q1,
                                float* __restrict__ out, uint4* __restrict__ zpg) {
  __shared__ float T[64 * 65];
  const int bx = blockIdx.x;
  if (bx < 8192) {
    int base = bx * 1024 + threadIdx.x;
#pragma unroll
    for (int i = 0; i < 4; ++i) {
      int gid = base + i * 256;
      float4 v = ((const float4*)x)[gid];
      ushort4 o;
      o.x = f2bf(v.x); o.y = f2bf(v.y); o.z = f2bf(v.z); o.w = f2bf(v.w);
      ((ushort4*)xb)[gid] = o;
    }
  } else if (bx < 8704) {
    const int u = bx - 8192;
    const int j0 = (u & 31) * 64;
    const int k0 = (u >> 5) * 64;
    const int jl = threadIdx.x & 63;
    const int q  = threadIdx.x >> 6;
    const float* src = (k0 < 512) ? (W + (size_t)k0 * 3072) : (V + (size_t)(k0 - 512) * 3072);
#pragma unroll 4
    for (int i = 0; i < 16; ++i) {
      int kl = q * 16 + i;
      T[kl * 65 + jl] = src[(size_t)kl * 3072 + j0 + jl];
    }
    __syncthreads();
    const int kl = threadIdx.x & 63;
#pragma unroll 4
    for (int i = 0; i < 16; ++i) {
      int jj = q * 16 + i;
      U[(size_t)(j0 + jj) * 1024 + k0 + kl] = f2bf(T[kl * 65 + jj]);
    }
  } else if (bx < 8832) {
    int gid = (bx - 8704) * 256 + threadIdx.x;   // 32768
    q0[gid] = b0[gid & 1023];
    q1[gid] = b1[gid & 1023];
    if (gid < 4096) out[gid] = b2[gid & 127];
  } else {
    zpg[threadIdx.x] = make_uint4(0u, 0u, 0u, 0u);   // 4 KB zeros
  }
}

// ---------------- main (bf16 path): 128^2 4-wave, 4 blocks/CU, gload_lds ----------------
// grid 8192 (1D, XCD-chunked), block 256 (waves: wm=wid>>1 x wn=wid&1)
// per wave: 64 t-rows x 64 cols -> acc[4][4] f32x4 (64 AGPR).
__global__ __launch_bounds__(256, 4) void qrnn_main4(
    const unsigned short* __restrict__ wsb, const float* __restrict__ Vb,
    float* __restrict__ Fagg, float* __restrict__ Zagg) {
  __shared__ __align__(16) char smem[36864];   // 2 ring slots x 16KB; epilogue overlay

  // XCD-chunked swizzle (same as r5): nwg=8192, %8==0 -> bijective. The 16
  // dt-blocks sharing a (b,cj) A-panel are consecutive in orig -> same XCD.
  const int bid  = blockIdx.x;
  const int orig = (bid & 7) * 1024 + (bid >> 3);
  const int dt = orig & 15;
  const int cj = (orig >> 4) & 15;
  const int b  = orig >> 8;

  const int tid = threadIdx.x;
  const int lane = tid & 63;
  const int wid  = tid >> 6;
  const int wm = wid >> 1, wn = wid & 1;
  const int l15 = lane & 15, lc = lane >> 4;
  const int s0 = cj * 128;

  f32x4 acc[4][4];
#pragma unroll
  for (int i = 0; i < 4; ++i)
#pragma unroll
    for (int j = 0; j < 4; ++j) acc[i][j] = f32x4{0.f, 0.f, 0.f, 0.f};

  // ---- per-lane staging source offsets (bf16 elements rel. wsb) ----
  // wave w stages A rows [w*32,w*32+32) and B rows same; 2 instr each (16 rows).
  // lane l -> row_g = base + (l>>2), phys 16B-slot p = l&3; source uses logical
  // slot q = p ^ ((row_g>>1)&3) (involution) so swizzled reads see linear data.
  unsigned eAx[2], eAp[2], eB[2];
#pragma unroll
  for (int i = 0; i < 2; ++i) {
    int row_g = wid * 32 + i * 16 + (lane >> 2);          // 0..127
    int q = (lane & 3) ^ ((row_g >> 1) & 3);
    int tx = s0 + row_g;                                  // ksteps 0..15: x[t]
    eAx[i] = XB_OFF_E + (unsigned)(b * 2048 + tx) * 512u + (unsigned)(q * 8);
    int tp = s0 - 1 + row_g;                              // ksteps 16..31: x[t-1]
    eAp[i] = (tp < 0) ? (ZERO_OFF_E + (unsigned)(q * 8))
                      : (XB_OFF_E + (unsigned)(b * 2048 + tp) * 512u + (unsigned)(q * 8));
    // B rows: col 0..63 -> f-gate U row dt*64+col; 64..127 -> z-gate 1024+dt*64+(col-64)
    int jj = (row_g < 64) ? (dt * 64 + row_g) : (1024 + dt * 64 + (row_g - 64));
    eB[i] = (unsigned)jj * 1024u + (unsigned)(q * 8);
  }

  // ---- fragment read offsets (swizzle lc ^ ((l15>>1)&3); row-base mult of 16) ----
  const unsigned swz = (unsigned)((lc ^ ((l15 >> 1) & 3)) << 4);
  const unsigned oA = (unsigned)((wm * 64 + l15) * 64) + swz;            // A rows
  const unsigned oB = 8192u + (unsigned)((wn * 64 + l15) * 64) + swz;    // B rows

  auto stage = [&](int kt, int slot) {
    const unsigned sbase = (unsigned)(slot * 16384);
    const bool xp = (kt < 16);
    const unsigned kaddA = xp ? (unsigned)(kt * 32) : (unsigned)((kt - 16) * 32);
    const unsigned kaddB = (unsigned)(kt * 32);
#pragma unroll
    for (int i = 0; i < 2; ++i) {
      unsigned da = (unsigned)__builtin_amdgcn_readfirstlane(
          (int)(sbase + (unsigned)(wid * 2048 + i * 1024)));
      gload_lds16(wsb + ((xp ? eAx[i] : eAp[i]) + kaddA), smem + da);
    }
#pragma unroll
    for (int i = 0; i < 2; ++i) {
      unsigned db = (unsigned)__builtin_amdgcn_readfirstlane(
          (int)(sbase + 8192u + (unsigned)(wid * 2048 + i * 1024)));
      gload_lds16(wsb + (eB[i] + kaddB), smem + db);
    }
  };

  // ---- prologue: slot 0 in flight (4 gloads) ----
  stage(0, 0);

  // One kstep: [vmcnt(0); barrier; stage(kt+1 -> buf^1); 8 ds_read(buf);
  // setprio(1); 16 MFMA; setprio(0)].
  // Ring-2 safety: buf^1's last readers were kstep kt-1, whose ds_reads
  // completed (lgkm-drained before their MFMAs) before the barrier at top of
  // this kstep; the gloads land by the NEXT kstep's vmcnt(0)+barrier.
  // The vmcnt(0) drain is hidden by the 3 other resident blocks (m114).
#define KSTEP(KT, SLOT)                                                              \
  {                                                                                  \
    const int kt = (KT);                                                             \
    asm volatile("s_waitcnt vmcnt(0)" ::: "memory");                                 \
    __builtin_amdgcn_s_barrier();                                                    \
    if (kt < 31) stage(kt + 1, (SLOT) ^ 1);                                          \
    const char* buf = smem + (SLOT) * 16384;                                         \
    short8 afr[4], bfr[4];                                                           \
    _Pragma("unroll")                                                                \
    for (int nt = 0; nt < 4; ++nt) bfr[nt] = *(const short8*)(buf + oB + nt * 1024); \
    _Pragma("unroll")                                                                \
    for (int mt = 0; mt < 4; ++mt) afr[mt] = *(const short8*)(buf + oA + mt * 1024); \
    __builtin_amdgcn_s_setprio(1);                                                   \
    _Pragma("unroll")                                                                \
    for (int mt = 0; mt < 4; ++mt)                                                   \
      _Pragma("unroll")                                                              \
      for (int nt = 0; nt < 4; ++nt)                                                 \
        acc[mt][nt] =                                                                \
            __builtin_amdgcn_mfma_f32_16x16x32_bf16(afr[mt], bfr[nt], acc[mt][nt], 0, 0, 0); \
    __builtin_amdgcn_s_setprio(0);                                                   \
  }

#pragma unroll 1
  for (int k2 = 0; k2 < 32; k2 += 2) {
    KSTEP(k2,     0);
    KSTEP(k2 + 1, 1);
  }
#undef KSTEP

  // ---- fused activations + scan (verified epilogue; 2 phases x 64 t) ----
  float* fA   = (float*)smem;            // [64][68]
  float* tzA  = (float*)(smem + 17408);  // [64][68]
  float* segF = (float*)(smem + 34816);  // [4][64]
  float* segZ = (float*)(smem + 35840);  // [4][64]

  const int d = tid & 63;
  float vb[4];
#pragma unroll
  for (int nt = 0; nt < 4; ++nt)
    vb[nt] = Vb[wn * 1024 + dt * 64 + nt * 16 + l15];

  float F_run = 1.f, Z_run = 0.f;

  for (int ph = 0; ph < 2; ++ph) {
    __syncthreads();
    if (wm == ph) {
      float* dst = (wn == 0) ? fA : tzA;
#pragma unroll
      for (int mt = 0; mt < 4; ++mt)
#pragma unroll
        for (int nt = 0; nt < 4; ++nt)
#pragma unroll
          for (int rg = 0; rg < 4; ++rg) {
            int t = mt * 16 + (lc << 2) + rg;   // phase-local 0..63
            int c = nt * 16 + l15;
            float v = acc[mt][nt][rg] + vb[nt];
            v = (wn == 0) ? sigmoidf_fast(v) : tanhf_fast(v);
            dst[t * 68 + c] = v;
          }
    }
    __syncthreads();
    {
      int seg = tid >> 6;
      float F = 1.f, Z = 0.f;
#pragma unroll 4
      for (int i = 0; i < 16; ++i) {
        int t = seg * 16 + i;
        float f  = fA[t * 68 + d];
        float tz = tzA[t * 68 + d];
        float z = (1.f - f) * tz;
        Z = f * Z + z;
        F *= f;
      }
      segF[seg * 64 + d] = F;
      segZ[seg * 64 + d] = Z;
    }
    __syncthreads();
    if (tid < 64) {
#pragma unroll
      for (int sgi = 0; sgi < 4; ++sgi) {
        float Fs = segF[sgi * 64 + tid], Zs = segZ[sgi * 64 + tid];
        Z_run = Fs * Z_run + Zs;
        F_run *= Fs;
      }
    }
  }
  if (tid < 64) {
    size_t o = (((size_t)b * 16 + cj) << 10) + dt * 64 + tid;
    Fagg[o] = F_run;
    Zagg[o] = Z_run;
  }
}

// ---------------- fallback (f32 path, 16-chunk layout) — previous verified kernel ----------------
template <bool USE_BF>
__global__ __launch_bounds__(256, 3) void qrnn_main(
    const unsigned short* __restrict__ wsb, const float* __restrict__ xf,
    const float* __restrict__ Vb,
    float* __restrict__ Fagg, float* __restrict__ Zagg) {
  __shared__ __align__(16) char smem[36864];

  const int dt = blockIdx.x;
  const int cj = blockIdx.y;
  const int b  = blockIdx.z;
  const int tid = threadIdx.x;
  const int lane = tid & 63;
  const int wid  = tid >> 6;
  const int wm = wid >> 1, wn = wid & 1;
  const int s0 = cj * 128;
  const int l15 = lane & 15, lc = lane >> 4;

  f32x4 acc[4][4];
#pragma unroll
  for (int i = 0; i < 4; ++i)
#pragma unroll
    for (int j = 0; j < 4; ++j) acc[i][j] = f32x4{0.f, 0.f, 0.f, 0.f};

  unsigned voffA[2];
  size_t offAF[2]; int zAF[2];
#pragma unroll
  for (int p = 0; p < 2; ++p) {
    int cw = tid + p * 256;
    int r = cw >> 2, c = cw & 3;
    int sg = s0 - 1 + r;
    voffA[p] = (sg < 0) ? (ZERO_OFF_E + (unsigned)(c * 8))
                        : (XB_OFF_E + (unsigned)(b * 2048 + sg) * 512u + (unsigned)(c * 8));
    zAF[p] = (sg < 0);
    offAF[p] = ((size_t)(b * 2048 + (sg < 0 ? 0 : sg)) << 9) + c * 8;
  }
  unsigned voffA3 = XB_OFF_E + (unsigned)(b * 2048 + s0 + 127) * 512u + (unsigned)((tid & 3) * 8);
  size_t offAF3 = ((size_t)(b * 2048 + s0 + 127) << 9) + (tid & 3) * 8;

  unsigned voffU[4];
#pragma unroll
  for (int k = 0; k < 4; ++k) {
    int uw = tid + k * 256;
    int r = uw >> 2, c = uw & 3;
    int col = r & 127, half = r >> 7;
    int j = (col < 64) ? (dt * 64 + col) : (1024 + dt * 64 + (col - 64));
    voffU[k] = (unsigned)(j * 1024 + half * 512 + c * 8);
  }

  unsigned wA[2], wU[4];
#pragma unroll
  for (int p = 0; p < 2; ++p) {
    int cw = tid + p * 256;
    wA[p] = stage_addr(cw >> 2, cw & 3);
  }
  const unsigned wA3 = stage_addr(128, tid & 3);
#pragma unroll
  for (int k = 0; k < 4; ++k) {
    int uw = tid + k * 256;
    wU[k] = U_LDS_BASE + stage_addr(uw >> 2, uw & 3);
  }

  unsigned roA[2][4], roU[2][4];
#pragma unroll
  for (int h2 = 0; h2 < 2; ++h2) {
#pragma unroll
    for (int mt = 0; mt < 4; ++mt) {
      int rr = wm * 64 + l15 + mt * 16 + 1 - h2;
      roA[h2][mt] = stage_addr(rr, lc);
    }
#pragma unroll
    for (int nt = 0; nt < 4; ++nt) {
      int rrU = h2 * 128 + wn * 64 + l15 + nt * 16;
      roU[h2][nt] = U_LDS_BASE + stage_addr(rrU, lc);
    }
  }

  uint4 pA0, pA1, pA3, pU0, pU1, pU2, pU3;

  auto load_stage = [&](int s) {
    const unsigned short* cur = wsb + s * 32;
    if constexpr (USE_BF) {
      pA0 = *(const uint4*)(cur + voffA[0]);
      pA1 = *(const uint4*)(cur + voffA[1]);
      if (tid < 4) pA3 = *(const uint4*)(cur + voffA3);
    } else {
      const float* curf = xf + s * 32;
#pragma unroll
      for (int p = 0; p < 2; ++p) {
        uint4 v = make_uint4(0u, 0u, 0u, 0u);
        if (!zAF[p]) {
          float4 a0 = *(const float4*)(curf + offAF[p]);
          float4 a1 = *(const float4*)(curf + offAF[p] + 4);
          v.x = (unsigned)f2bf(a0.x) | ((unsigned)f2bf(a0.y) << 16);
          v.y = (unsigned)f2bf(a0.z) | ((unsigned)f2bf(a0.w) << 16);
          v.z = (unsigned)f2bf(a1.x) | ((unsigned)f2bf(a1.y) << 16);
          v.w = (unsigned)f2bf(a1.z) | ((unsigned)f2bf(a1.w) << 16);
        }
        if (p == 0) pA0 = v; else pA1 = v;
      }
      if (tid < 4) {
        float4 a0 = *(const float4*)(curf + offAF3);
        float4 a1 = *(const float4*)(curf + offAF3 + 4);
        pA3.x = (unsigned)f2bf(a0.x) | ((unsigned)f2bf(a0.y) << 16);
        pA3.y = (unsigned)f2bf(a0.z) | ((unsigned)f2bf(a0.w) << 16);
        pA3.z = (unsigned)f2bf(a1.x) | ((unsigned)f2bf(a1.y) << 16);
        pA3.w = (unsigned)f2bf(a1.z) | ((unsigned)f2bf(a1.w) << 16);
      }
    }
    pU0 = *(const uint4*)(cur + voffU[0]);
    pU1 = *(const uint4*)(cur + voffU[1]);
    pU2 = *(const uint4*)(cur + voffU[2]);
    pU3 = *(const uint4*)(cur + voffU[3]);
  };

  load_stage(0);

#pragma unroll 1
  for (int s = 0; s < 16; ++s) {
    __syncthreads();
    *(uint4*)(smem + wA[0]) = pA0;
    *(uint4*)(smem + wA[1]) = pA1;
    if (tid < 4) *(uint4*)(smem + wA3) = pA3;
    *(uint4*)(smem + wU[0]) = pU0;
    *(uint4*)(smem + wU[1]) = pU1;
    *(uint4*)(smem + wU[2]) = pU2;
    *(uint4*)(smem + wU[3]) = pU3;
    __syncthreads();
    if (s < 15) load_stage(s + 1);
#pragma unroll
    for (int h2 = 0; h2 < 2; ++h2) {
      short8 bfr[4];
#pragma unroll
      for (int nt = 0; nt < 4; ++nt)
        bfr[nt] = *(const short8*)(smem + roU[h2][nt]);
#pragma unroll
      for (int mt = 0; mt < 4; ++mt) {
        short8 afr = *(const short8*)(smem + roA[h2][mt]);
#pragma unroll
        for (int nt = 0; nt < 4; ++nt)
          acc[mt][nt] = __builtin_amdgcn_mfma_f32_16x16x32_bf16(afr, bfr[nt], acc[mt][nt], 0, 0, 0);
      }
    }
  }

  float* fA   = (float*)smem;
  float* tzA  = (float*)(smem + 17408);
  float* segF = (float*)(smem + 34816);
  float* segZ = (float*)(smem + 35840);

  const int d = tid & 63;
  float vb[4];
#pragma unroll
  for (int nt = 0; nt < 4; ++nt)
    vb[nt] = Vb[wn * 1024 + dt * 64 + nt * 16 + l15];

  float F_run = 1.f, Z_run = 0.f;

  for (int ph = 0; ph < 2; ++ph) {
    __syncthreads();
    if (wm == ph) {
      float* dst = (wn == 0) ? fA : tzA;
#pragma unroll
      for (int mt = 0; mt < 4; ++mt)
#pragma unroll
        for (int nt = 0; nt < 4; ++nt)
#pragma unroll
          for (int rg = 0; rg < 4; ++rg) {
            int t = mt * 16 + ((lane >> 4) << 2) + rg;
            int c = nt * 16 + l15;
            float v = acc[mt][nt][rg] + vb[nt];
            v = (wn == 0) ? sigmoidf_fast(v) : tanhf_fast(v);
            dst[t * 68 + c] = v;
          }
    }
    __syncthreads();
    {
      int seg = tid >> 6;
      float F = 1.f, Z = 0.f;
#pragma unroll 4
      for (int i = 0; i < 16; ++i) {
        int t = seg * 16 + i;
        float f  = fA[t * 68 + d];
        float tz = tzA[t * 68 + d];
        float z = (1.f - f) * tz;
        Z = f * Z + z;
        F *= f;
      }
      segF[seg * 64 + d] = F;
      segZ[seg * 64 + d] = Z;
    }
    __syncthreads();
    if (tid < 64) {
#pragma unroll
      for (int sgi = 0; sgi < 4; ++sgi) {
        float Fs = segF[sgi * 64 + tid], Zs = segZ[sgi * 64 + tid];
        Z_run = Fs * Z_run + Zs;
        F_run *= Fs;
      }
    }
  }
  if (tid < 64) {
    size_t o = (((size_t)b * 16 + cj) << 10) + dt * 64 + tid;
    Fagg[o] = F_run;
    Zagg[o] = Z_run;
  }
}

// ---------------- head: K-split o-gate + nch-chunk combine ----------------
// grid (16 dtile, 32 b), block 256 = 64 d x 4 k-segments
__global__ void head_kernel(const float* __restrict__ x, const float* __restrict__ W,
                            const float* __restrict__ V, const float* __restrict__ Vb,
                            const float* __restrict__ Fagg, const float* __restrict__ Zagg,
                            float* __restrict__ h, int nch) {
  __shared__ float red[4][64];
  const int dl = threadIdx.x & 63;
  const int w  = threadIdx.x >> 6;
  const int d = blockIdx.x * 64 + dl;
  const int b = blockIdx.y;

  const float* xl = x + ((size_t)b * 2048 + 2047) * 512;
  const float* xp = xl - 512;
  const float* Wc = W + 2048 + d;
  const float* Vc = V + 2048 + d;
  float po = 0.f;
  const int k0 = w * 128;
#pragma unroll 8
  for (int k = k0; k < k0 + 128; ++k) {
    po += xl[k] * Wc[(size_t)k * 3072];
    po += xp[k] * Vc[(size_t)k * 3072];
  }
  red[w][dl] = po;
  __syncthreads();
  if (w == 0) {
    po = red[0][dl] + red[1][dl] + red[2][dl] + red[3][dl] + Vb[2048 + d];
    float c = 0.f;
    for (int j = 0; j < nch; ++j) {
      size_t o = (((size_t)b * nch + j) << 10) + d;
      c = Fagg[o] * c + Zagg[o];
    }
    h[((size_t)b << 10) + d] = c * sigmoidf_fast(po);
  }
}

// ---------------- MLP: K-split atomic GEMV (ReLU on input) ----------------
// grid (N/64, B, 4 ksplit), block 256 = 64 n x 4 waves
__global__ void mlp_atomic_kernel(const float* __restrict__ in, const float* __restrict__ Wt,
                                  float* __restrict__ out, int K, int N, int relu_in) {
  __shared__ float red[4][64];
  const int nl = threadIdx.x & 63;
  const int w  = threadIdx.x >> 6;
  const int n = blockIdx.x * 64 + nl;
  const int b = blockIdx.y;
  const int k0 = blockIdx.z * (K >> 2) + w * (K >> 4);
  const float* row = in + (size_t)b * K;
  const float* Wc = Wt + n;
  float s = 0.f;
#pragma unroll 8
  for (int k = k0; k < k0 + (K >> 4); ++k) {
    float v = row[k];
    if (relu_in) v = fmaxf(v, 0.f);
    s += v * Wc[(size_t)k * N];
  }
  red[w][nl] = s;
  __syncthreads();
  if (w == 0) {
    s = red[0][nl] + red[1][nl] + red[2][nl] + red[3][nl];
    atomicAdd(&out[(size_t)b * N + n], s);
  }
}

extern "C" void kernel_launch(void* const* d_in, const int* in_sizes, int n_in,
                              void* d_out, int out_size, void* d_ws, size_t ws_size,
                              hipStream_t stream) {
  const float* x  = (const float*)d_in[0];
  const float* W  = (const float*)d_in[1];
  const float* V  = (const float*)d_in[2];
  const float* Vb = (const float*)d_in[3];
  const float* W0 = (const float*)d_in[4];
  const float* b0 = (const float*)d_in[5];
  const float* W1 = (const float*)d_in[6];
  const float* b1 = (const float*)d_in[7];
  const float* W2 = (const float*)d_in[8];
  const float* b2 = (const float*)d_in[9];

  char* ws = (char*)d_ws;
  unsigned short* U = (unsigned short*)(ws);                              // 4 MiB
  float* Fagg = (float*)(ws + (size_t)4 * 1024 * 1024);                   // 2 MiB
  float* Zagg = (float*)(ws + (size_t)6 * 1024 * 1024);                   // 2 MiB
  float* h    = (float*)(ws + (size_t)8 * 1024 * 1024);                   // 128 KiB
  float* q0   = (float*)(ws + (size_t)8 * 1024 * 1024 + 256 * 1024);
  float* q1   = (float*)(ws + (size_t)8 * 1024 * 1024 + 512 * 1024);
  uint4* zpg  = (uint4*)(ws + (size_t)12 * 1024 * 1024);                  // 4 KiB zeros
  unsigned short* xb = (unsigned short*)(ws + (size_t)16 * 1024 * 1024);  // 64 MiB

  const size_t need_bf = (size_t)16 * 1024 * 1024 + (size_t)67108864;
  int use_bf = (ws_size >= need_bf) ? 1 : 0;   // constant across calls -> graph-safe

  prologue_kernel<<<8833, 256, 0, stream>>>(x, W, V, b0, b1, b2, xb, U, q0, q1,
                                            (float*)d_out, zpg);
  if (use_bf) {
    qrnn_main4<<<8192, 256, 0, stream>>>((const unsigned short*)ws, Vb, Fagg, Zagg);
  } else {
    qrnn_main<false><<<dim3(16, 16, 32), 256, 0, stream>>>((const unsigned short*)ws, x,
                                                           Vb, Fagg, Zagg);
  }
  head_kernel<<<dim3(16, 32), 256, 0, stream>>>(x, W, V, Vb, Fagg, Zagg, h, 16);
  mlp_atomic_kernel<<<dim3(16, 32, 4), 256, 0, stream>>>(h, W0, q0, 1024, 1024, 0);
  mlp_atomic_kernel<<<dim3(16, 32, 4), 256, 0, stream>>>(q0, W1, q1, 1024, 1024, 1);
  mlp_atomic_kernel<<<dim3(2, 32, 4), 256, 0, stream>>>(q1, W2, (float*)d_out, 1024, 128, 1);
}

// Round 7
// 617.934 us; speedup vs baseline: 1.0421x; 1.0235x over previous
//
#include <hip/hip_runtime.h>
#include <cstdint>
#include <cstddef>

// QRNN fused pipeline for MI355X (gfx950).
// B=32, S=2048, D_in=512, D_model=1024, D_mlp=1024, n_cls=128.
//
// ws layout (bytes): U bf16 [2048][1024] @0 (4MB) | Fagg @4MB | Zagg @6MB |
//   h @8MB | q0 @8MB+256K | q1 @8MB+512K | zero page @12MB (4KB) | xb bf16 @16MB (64MB)
//
// qrnn_main4 (round 7): r6's 4-blocks/CU structure with its two measured
// regressions removed:
//  1) NATURAL grid (16,16,32), dt fastest (r0 dispatch): XCD i sees only
//     dt in {i,i+8} -> 512 KB U slice stays L2-resident (r6's (b,cj)-chunked
//     swizzle thrashed the 4MB L2 with the full 4MB U: FETCH 497 MB).
//  2) Spill fix: r6's launch_bounds(256,4) left only 64 VGPRs beside the 64
//     AGPR acc; 16 live afr+16 bfr forced ~9 dwords/thread scratch spill
//     (WRITE_SIZE 4->76 MB). Kstep now reads bfr[4] up front and afr ONE at
//     a time inside the mt loop (max live A-frag = 1).
// Everything else identical to r6 (PASSED): ring-2 LDS (2x16KB, 36864B with
// epilogue overlay), gload_lds staging, pre-swizzled conflict-free LDS
// (rule #21), structural xprev (ksteps 0..15 x[t]*W-half, 16..31 x[t-1]*
// V-half, zero page at t=-1), vmcnt(0)+barrier once per kstep, setprio(1)
// around the MFMA cluster, 16-chunk scan epilogue + head.

typedef __attribute__((ext_vector_type(8))) short short8;
typedef __attribute__((ext_vector_type(4))) float f32x4;

#define ZERO_OFF_E 6291456u    // 12MB / 2 (bf16 elements)
#define XB_OFF_E   8388608u    // 16MB / 2
#define U_LDS_BASE 8256        // (fallback kernel) A stage = 129 rows * 64B

__device__ __forceinline__ unsigned short f2bf(float f) {
  unsigned int u = __float_as_uint(f);
  u += 0x7fffu + ((u >> 16) & 1u);
  return (unsigned short)(u >> 16);
}

__device__ __forceinline__ unsigned stage_addr(int r, int c) {
  return (unsigned)(r * 64 + (((c + r + (r >> 2)) & 3) << 4));
}

__device__ __forceinline__ float sigmoidf_fast(float x) {
  return 1.f / (1.f + __expf(-x));
}
__device__ __forceinline__ float tanhf_fast(float x) {
  float a = fabsf(x);
  float e = __expf(-2.f * a);
  float t = (1.f - e) / (1.f + e);
  return copysignf(t, x);
}

// async 16B global->LDS. LDS dest must be wave-uniform base; lane lands at
// base + lane*16.
__device__ __forceinline__ void gload_lds16(const void* g, const char* lds) {
  __builtin_amdgcn_global_load_lds(
      (const __attribute__((address_space(1))) void*)(uintptr_t)g,
      (__attribute__((address_space(3))) void*)(uint32_t)(uintptr_t)lds, 16, 0, 0);
}

// ---------------- prologue ----------------
// grid 8833: [0,8192) pack_x (4 float4/thread); [8192,8704) pack_u; [8704,8832) init; 8832 zpg
__global__ void prologue_kernel(const float* __restrict__ x, const float* __restrict__ W,
                                const float* __restrict__ V,
                                const float* __restrict__ b0, const float* __restrict__ b1,
                                const float* __restrict__ b2,
                                unsigned short* __restrict__ xb, unsigned short* __restrict__ U,
                                float* __restrict__ q0, float* __restrict__ q1,
                                float* __restrict__ out, uint4* __restrict__ zpg) {
  __shared__ float T[64 * 65];
  const int bx = blockIdx.x;
  if (bx < 8192) {
    int base = bx * 1024 + threadIdx.x;
#pragma unroll
    for (int i = 0; i < 4; ++i) {
      int gid = base + i * 256;
      float4 v = ((const float4*)x)[gid];
      ushort4 o;
      o.x = f2bf(v.x); o.y = f2bf(v.y); o.z = f2bf(v.z); o.w = f2bf(v.w);
      ((ushort4*)xb)[gid] = o;
    }
  } else if (bx < 8704) {
    const int u = bx - 8192;
    const int j0 = (u & 31) * 64;
    const int k0 = (u >> 5) * 64;
    const int jl = threadIdx.x & 63;
    const int q  = threadIdx.x >> 6;
    const float* src = (k0 < 512) ? (W + (size_t)k0 * 3072) : (V + (size_t)(k0 - 512) * 3072);
#pragma unroll 4
    for (int i = 0; i < 16; ++i) {
      int kl = q * 16 + i;
      T[kl * 65 + jl] = src[(size_t)kl * 3072 + j0 + jl];
    }
    __syncthreads();
    const int kl = threadIdx.x & 63;
#pragma unroll 4
    for (int i = 0; i < 16; ++i) {
      int jj = q * 16 + i;
      U[(size_t)(j0 + jj) * 1024 + k0 + kl] = f2bf(T[kl * 65 + jj]);
    }
  } else if (bx < 8832) {
    int gid = (bx - 8704) * 256 + threadIdx.x;   // 32768
    q0[gid] = b0[gid & 1023];
    q1[gid] = b1[gid & 1023];
    if (gid < 4096) out[gid] = b2[gid & 127];
  } else {
    zpg[threadIdx.x] = make_uint4(0u, 0u, 0u, 0u);   // 4 KB zeros
  }
}

// ---------------- main (bf16 path): 128^2 4-wave, 4 blocks/CU, gload_lds ----------------
// grid (16 dt, 16 cj, 32 b) NATURAL dispatch (dt fastest -> per-XCD U slice
// L2-resident), block 256 (waves: wm=wid>>1 x wn=wid&1)
// per wave: 64 t-rows x 64 cols -> acc[4][4] f32x4 (64 AGPR).
__global__ __launch_bounds__(256, 4) void qrnn_main4(
    const unsigned short* __restrict__ wsb, const float* __restrict__ Vb,
    float* __restrict__ Fagg, float* __restrict__ Zagg) {
  __shared__ __align__(16) char smem[36864];   // 2 ring slots x 16KB; epilogue overlay

  const int dt = blockIdx.x;
  const int cj = blockIdx.y;
  const int b  = blockIdx.z;

  const int tid = threadIdx.x;
  const int lane = tid & 63;
  const int wid  = tid >> 6;
  const int wm = wid >> 1, wn = wid & 1;
  const int l15 = lane & 15, lc = lane >> 4;
  const int s0 = cj * 128;

  f32x4 acc[4][4];
#pragma unroll
  for (int i = 0; i < 4; ++i)
#pragma unroll
    for (int j = 0; j < 4; ++j) acc[i][j] = f32x4{0.f, 0.f, 0.f, 0.f};

  // ---- per-lane staging source offsets (bf16 elements rel. wsb) ----
  // wave w stages A rows [w*32,w*32+32) and B rows same; 2 instr each (16 rows).
  // lane l -> row_g = base + (l>>2), phys 16B-slot p = l&3; source uses logical
  // slot q = p ^ ((row_g>>1)&3) (involution) so swizzled reads see linear data.
  unsigned eAx[2], eAp[2], eB[2];
#pragma unroll
  for (int i = 0; i < 2; ++i) {
    int row_g = wid * 32 + i * 16 + (lane >> 2);          // 0..127
    int q = (lane & 3) ^ ((row_g >> 1) & 3);
    int tx = s0 + row_g;                                  // ksteps 0..15: x[t]
    eAx[i] = XB_OFF_E + (unsigned)(b * 2048 + tx) * 512u + (unsigned)(q * 8);
    int tp = s0 - 1 + row_g;                              // ksteps 16..31: x[t-1]
    eAp[i] = (tp < 0) ? (ZERO_OFF_E + (unsigned)(q * 8))
                      : (XB_OFF_E + (unsigned)(b * 2048 + tp) * 512u + (unsigned)(q * 8));
    // B rows: col 0..63 -> f-gate U row dt*64+col; 64..127 -> z-gate 1024+dt*64+(col-64)
    int jj = (row_g < 64) ? (dt * 64 + row_g) : (1024 + dt * 64 + (row_g - 64));
    eB[i] = (unsigned)jj * 1024u + (unsigned)(q * 8);
  }

  // ---- fragment read offsets (swizzle lc ^ ((l15>>1)&3); row-base mult of 16) ----
  const unsigned swz = (unsigned)((lc ^ ((l15 >> 1) & 3)) << 4);
  const unsigned oA = (unsigned)((wm * 64 + l15) * 64) + swz;            // A rows
  const unsigned oB = 8192u + (unsigned)((wn * 64 + l15) * 64) + swz;    // B rows

  auto stage = [&](int kt, int slot) {
    const unsigned sbase = (unsigned)(slot * 16384);
    const bool xp = (kt < 16);
    const unsigned kaddA = xp ? (unsigned)(kt * 32) : (unsigned)((kt - 16) * 32);
    const unsigned kaddB = (unsigned)(kt * 32);
#pragma unroll
    for (int i = 0; i < 2; ++i) {
      unsigned da = (unsigned)__builtin_amdgcn_readfirstlane(
          (int)(sbase + (unsigned)(wid * 2048 + i * 1024)));
      gload_lds16(wsb + ((xp ? eAx[i] : eAp[i]) + kaddA), smem + da);
    }
#pragma unroll
    for (int i = 0; i < 2; ++i) {
      unsigned db = (unsigned)__builtin_amdgcn_readfirstlane(
          (int)(sbase + 8192u + (unsigned)(wid * 2048 + i * 1024)));
      gload_lds16(wsb + (eB[i] + kaddB), smem + db);
    }
  };

  // ---- prologue: slot 0 in flight (4 gloads) ----
  stage(0, 0);

  // One kstep: [vmcnt(0); barrier; stage(kt+1 -> buf^1); 4 bfr ds_read;
  // setprio(1); per-mt {1 afr ds_read; 4 MFMA}; setprio(0)].
  // afr one-at-a-time keeps max live A-frags at 1 (r6's 4-deep afr[] +
  // bfr[] = 32 live VGPRs forced a ~9-dword scratch spill at the 64-VGPR
  // budget: WRITE_SIZE 76 MB).
  // Ring-2 safety: buf^1's last readers were kstep kt-1, whose ds_reads
  // completed (lgkm-drained before their consuming MFMAs) before this
  // kstep's barrier; the gloads land by the NEXT kstep's vmcnt(0)+barrier.
  // The vmcnt(0) drain is hidden by the 3 other resident blocks (m114).
#define KSTEP(KT, SLOT)                                                              \
  {                                                                                  \
    const int kt = (KT);                                                             \
    asm volatile("s_waitcnt vmcnt(0)" ::: "memory");                                 \
    __builtin_amdgcn_s_barrier();                                                    \
    if (kt < 31) stage(kt + 1, (SLOT) ^ 1);                                          \
    const char* buf = smem + (SLOT) * 16384;                                         \
    short8 bfr[4];                                                                   \
    _Pragma("unroll")                                                                \
    for (int nt = 0; nt < 4; ++nt) bfr[nt] = *(const short8*)(buf + oB + nt * 1024); \
    __builtin_amdgcn_s_setprio(1);                                                   \
    _Pragma("unroll")                                                                \
    for (int mt = 0; mt < 4; ++mt) {                                                 \
      short8 afr = *(const short8*)(buf + oA + mt * 1024);                           \
      _Pragma("unroll")                                                              \
      for (int nt = 0; nt < 4; ++nt)                                                 \
        acc[mt][nt] =                                                                \
            __builtin_amdgcn_mfma_f32_16x16x32_bf16(afr, bfr[nt], acc[mt][nt], 0, 0, 0); \
    }                                                                                \
    __builtin_amdgcn_s_setprio(0);                                                   \
  }

#pragma unroll 1
  for (int k2 = 0; k2 < 32; k2 += 2) {
    KSTEP(k2,     0);
    KSTEP(k2 + 1, 1);
  }
#undef KSTEP

  // ---- fused activations + scan (verified epilogue; 2 phases x 64 t) ----
  float* fA   = (float*)smem;            // [64][68]
  float* tzA  = (float*)(smem + 17408);  // [64][68]
  float* segF = (float*)(smem + 34816);  // [4][64]
  float* segZ = (float*)(smem + 35840);  // [4][64]

  const int d = tid & 63;
  float vb[4];
#pragma unroll
  for (int nt = 0; nt < 4; ++nt)
    vb[nt] = Vb[wn * 1024 + dt * 64 + nt * 16 + l15];

  float F_run = 1.f, Z_run = 0.f;

  for (int ph = 0; ph < 2; ++ph) {
    __syncthreads();
    if (wm == ph) {
      float* dst = (wn == 0) ? fA : tzA;
#pragma unroll
      for (int mt = 0; mt < 4; ++mt)
#pragma unroll
        for (int nt = 0; nt < 4; ++nt)
#pragma unroll
          for (int rg = 0; rg < 4; ++rg) {
            int t = mt * 16 + (lc << 2) + rg;   // phase-local 0..63
            int c = nt * 16 + l15;
            float v = acc[mt][nt][rg] + vb[nt];
            v = (wn == 0) ? sigmoidf_fast(v) : tanhf_fast(v);
            dst[t * 68 + c] = v;
          }
    }
    __syncthreads();
    {
      int seg = tid >> 6;
      float F = 1.f, Z = 0.f;
#pragma unroll 4
      for (int i = 0; i < 16; ++i) {
        int t = seg * 16 + i;
        float f  = fA[t * 68 + d];
        float tz = tzA[t * 68 + d];
        float z = (1.f - f) * tz;
        Z = f * Z + z;
        F *= f;
      }
      segF[seg * 64 + d] = F;
      segZ[seg * 64 + d] = Z;
    }
    __syncthreads();
    if (tid < 64) {
#pragma unroll
      for (int sgi = 0; sgi < 4; ++sgi) {
        float Fs = segF[sgi * 64 + tid], Zs = segZ[sgi * 64 + tid];
        Z_run = Fs * Z_run + Zs;
        F_run *= Fs;
      }
    }
  }
  if (tid < 64) {
    size_t o = (((size_t)b * 16 + cj) << 10) + dt * 64 + tid;
    Fagg[o] = F_run;
    Zagg[o] = Z_run;
  }
}

// ---------------- fallback (f32 path, 16-chunk layout) — previous verified kernel ----------------
template <bool USE_BF>
__global__ __launch_bounds__(256, 3) void qrnn_main(
    const unsigned short* __restrict__ wsb, const float* __restrict__ xf,
    const float* __restrict__ Vb,
    float* __restrict__ Fagg, float* __restrict__ Zagg) {
  __shared__ __align__(16) char smem[36864];

  const int dt = blockIdx.x;
  const int cj = blockIdx.y;
  const int b  = blockIdx.z;
  const int tid = threadIdx.x;
  const int lane = tid & 63;
  const int wid  = tid >> 6;
  const int wm = wid >> 1, wn = wid & 1;
  const int s0 = cj * 128;
  const int l15 = lane & 15, lc = lane >> 4;

  f32x4 acc[4][4];
#pragma unroll
  for (int i = 0; i < 4; ++i)
#pragma unroll
    for (int j = 0; j < 4; ++j) acc[i][j] = f32x4{0.f, 0.f, 0.f, 0.f};

  unsigned voffA[2];
  size_t offAF[2]; int zAF[2];
#pragma unroll
  for (int p = 0; p < 2; ++p) {
    int cw = tid + p * 256;
    int r = cw >> 2, c = cw & 3;
    int sg = s0 - 1 + r;
    voffA[p] = (sg < 0) ? (ZERO_OFF_E + (unsigned)(c * 8))
                        : (XB_OFF_E + (unsigned)(b * 2048 + sg) * 512u + (unsigned)(c * 8));
    zAF[p] = (sg < 0);
    offAF[p] = ((size_t)(b * 2048 + (sg < 0 ? 0 : sg)) << 9) + c * 8;
  }
  unsigned voffA3 = XB_OFF_E + (unsigned)(b * 2048 + s0 + 127) * 512u + (unsigned)((tid & 3) * 8);
  size_t offAF3 = ((size_t)(b * 2048 + s0 + 127) << 9) + (tid & 3) * 8;

  unsigned voffU[4];
#pragma unroll
  for (int k = 0; k < 4; ++k) {
    int uw = tid + k * 256;
    int r = uw >> 2, c = uw & 3;
    int col = r & 127, half = r >> 7;
    int j = (col < 64) ? (dt * 64 + col) : (1024 + dt * 64 + (col - 64));
    voffU[k] = (unsigned)(j * 1024 + half * 512 + c * 8);
  }

  unsigned wA[2], wU[4];
#pragma unroll
  for (int p = 0; p < 2; ++p) {
    int cw = tid + p * 256;
    wA[p] = stage_addr(cw >> 2, cw & 3);
  }
  const unsigned wA3 = stage_addr(128, tid & 3);
#pragma unroll
  for (int k = 0; k < 4; ++k) {
    int uw = tid + k * 256;
    wU[k] = U_LDS_BASE + stage_addr(uw >> 2, uw & 3);
  }

  unsigned roA[2][4], roU[2][4];
#pragma unroll
  for (int h2 = 0; h2 < 2; ++h2) {
#pragma unroll
    for (int mt = 0; mt < 4; ++mt) {
      int rr = wm * 64 + l15 + mt * 16 + 1 - h2;
      roA[h2][mt] = stage_addr(rr, lc);
    }
#pragma unroll
    for (int nt = 0; nt < 4; ++nt) {
      int rrU = h2 * 128 + wn * 64 + l15 + nt * 16;
      roU[h2][nt] = U_LDS_BASE + stage_addr(rrU, lc);
    }
  }

  uint4 pA0, pA1, pA3, pU0, pU1, pU2, pU3;

  auto load_stage = [&](int s) {
    const unsigned short* cur = wsb + s * 32;
    if constexpr (USE_BF) {
      pA0 = *(const uint4*)(cur + voffA[0]);
      pA1 = *(const uint4*)(cur + voffA[1]);
      if (tid < 4) pA3 = *(const uint4*)(cur + voffA3);
    } else {
      const float* curf = xf + s * 32;
#pragma unroll
      for (int p = 0; p < 2; ++p) {
        uint4 v = make_uint4(0u, 0u, 0u, 0u);
        if (!zAF[p]) {
          float4 a0 = *(const float4*)(curf + offAF[p]);
          float4 a1 = *(const float4*)(curf + offAF[p] + 4);
          v.x = (unsigned)f2bf(a0.x) | ((unsigned)f2bf(a0.y) << 16);
          v.y = (unsigned)f2bf(a0.z) | ((unsigned)f2bf(a0.w) << 16);
          v.z = (unsigned)f2bf(a1.x) | ((unsigned)f2bf(a1.y) << 16);
          v.w = (unsigned)f2bf(a1.z) | ((unsigned)f2bf(a1.w) << 16);
        }
        if (p == 0) pA0 = v; else pA1 = v;
      }
      if (tid < 4) {
        float4 a0 = *(const float4*)(curf + offAF3);
        float4 a1 = *(const float4*)(curf + offAF3 + 4);
        pA3.x = (unsigned)f2bf(a0.x) | ((unsigned)f2bf(a0.y) << 16);
        pA3.y = (unsigned)f2bf(a0.z) | ((unsigned)f2bf(a0.w) << 16);
        pA3.z = (unsigned)f2bf(a1.x) | ((unsigned)f2bf(a1.y) << 16);
        pA3.w = (unsigned)f2bf(a1.z) | ((unsigned)f2bf(a1.w) << 16);
      }
    }
    pU0 = *(const uint4*)(cur + voffU[0]);
    pU1 = *(const uint4*)(cur + voffU[1]);
    pU2 = *(const uint4*)(cur + voffU[2]);
    pU3 = *(const uint4*)(cur + voffU[3]);
  };

  load_stage(0);

#pragma unroll 1
  for (int s = 0; s < 16; ++s) {
    __syncthreads();
    *(uint4*)(smem + wA[0]) = pA0;
    *(uint4*)(smem + wA[1]) = pA1;
    if (tid < 4) *(uint4*)(smem + wA3) = pA3;
    *(uint4*)(smem + wU[0]) = pU0;
    *(uint4*)(smem + wU[1]) = pU1;
    *(uint4*)(smem + wU[2]) = pU2;
    *(uint4*)(smem + wU[3]) = pU3;
    __syncthreads();
    if (s < 15) load_stage(s + 1);
#pragma unroll
    for (int h2 = 0; h2 < 2; ++h2) {
      short8 bfr[4];
#pragma unroll
      for (int nt = 0; nt < 4; ++nt)
        bfr[nt] = *(const short8*)(smem + roU[h2][nt]);
#pragma unroll
      for (int mt = 0; mt < 4; ++mt) {
        short8 afr = *(const short8*)(smem + roA[h2][mt]);
#pragma unroll
        for (int nt = 0; nt < 4; ++nt)
          acc[mt][nt] = __builtin_amdgcn_mfma_f32_16x16x32_bf16(afr, bfr[nt], acc[mt][nt], 0, 0, 0);
      }
    }
  }

  float* fA   = (float*)smem;
  float* tzA  = (float*)(smem + 17408);
  float* segF = (float*)(smem + 34816);
  float* segZ = (float*)(smem + 35840);

  const int d = tid & 63;
  float vb[4];
#pragma unroll
  for (int nt = 0; nt < 4; ++nt)
    vb[nt] = Vb[wn * 1024 + dt * 64 + nt * 16 + l15];

  float F_run = 1.f, Z_run = 0.f;

  for (int ph = 0; ph < 2; ++ph) {
    __syncthreads();
    if (wm == ph) {
      float* dst = (wn == 0) ? fA : tzA;
#pragma unroll
      for (int mt = 0; mt < 4; ++mt)
#pragma unroll
        for (int nt = 0; nt < 4; ++nt)
#pragma unroll
          for (int rg = 0; rg < 4; ++rg) {
            int t = mt * 16 + ((lane >> 4) << 2) + rg;
            int c = nt * 16 + l15;
            float v = acc[mt][nt][rg] + vb[nt];
            v = (wn == 0) ? sigmoidf_fast(v) : tanhf_fast(v);
            dst[t * 68 + c] = v;
          }
    }
    __syncthreads();
    {
      int seg = tid >> 6;
      float F = 1.f, Z = 0.f;
#pragma unroll 4
      for (int i = 0; i < 16; ++i) {
        int t = seg * 16 + i;
        float f  = fA[t * 68 + d];
        float tz = tzA[t * 68 + d];
        float z = (1.f - f) * tz;
        Z = f * Z + z;
        F *= f;
      }
      segF[seg * 64 + d] = F;
      segZ[seg * 64 + d] = Z;
    }
    __syncthreads();
    if (tid < 64) {
#pragma unroll
      for (int sgi = 0; sgi < 4; ++sgi) {
        float Fs = segF[sgi * 64 + tid], Zs = segZ[sgi * 64 + tid];
        Z_run = Fs * Z_run + Zs;
        F_run *= Fs;
      }
    }
  }
  if (tid < 64) {
    size_t o = (((size_t)b * 16 + cj) << 10) + dt * 64 + tid;
    Fagg[o] = F_run;
    Zagg[o] = Z_run;
  }
}

// ---------------- head: K-split o-gate + nch-chunk combine ----------------
// grid (16 dtile, 32 b), block 256 = 64 d x 4 k-segments
__global__ void head_kernel(const float* __restrict__ x, const float* __restrict__ W,
                            const float* __restrict__ V, const float* __restrict__ Vb,
                            const float* __restrict__ Fagg, const float* __restrict__ Zagg,
                            float* __restrict__ h, int nch) {
  __shared__ float red[4][64];
  const int dl = threadIdx.x & 63;
  const int w  = threadIdx.x >> 6;
  const int d = blockIdx.x * 64 + dl;
  const int b = blockIdx.y;

  const float* xl = x + ((size_t)b * 2048 + 2047) * 512;
  const float* xp = xl - 512;
  const float* Wc = W + 2048 + d;
  const float* Vc = V + 2048 + d;
  float po = 0.f;
  const int k0 = w * 128;
#pragma unroll 8
  for (int k = k0; k < k0 + 128; ++k) {
    po += xl[k] * Wc[(size_t)k * 3072];
    po += xp[k] * Vc[(size_t)k * 3072];
  }
  red[w][dl] = po;
  __syncthreads();
  if (w == 0) {
    po = red[0][dl] + red[1][dl] + red[2][dl] + red[3][dl] + Vb[2048 + d];
    float c = 0.f;
    for (int j = 0; j < nch; ++j) {
      size_t o = (((size_t)b * nch + j) << 10) + d;
      c = Fagg[o] * c + Zagg[o];
    }
    h[((size_t)b << 10) + d] = c * sigmoidf_fast(po);
  }
}

// ---------------- MLP: K-split atomic GEMV (ReLU on input) ----------------
// grid (N/64, B, 4 ksplit), block 256 = 64 n x 4 waves
__global__ void mlp_atomic_kernel(const float* __restrict__ in, const float* __restrict__ Wt,
                                  float* __restrict__ out, int K, int N, int relu_in) {
  __shared__ float red[4][64];
  const int nl = threadIdx.x & 63;
  const int w  = threadIdx.x >> 6;
  const int n = blockIdx.x * 64 + nl;
  const int b = blockIdx.y;
  const int k0 = blockIdx.z * (K >> 2) + w * (K >> 4);
  const float* row = in + (size_t)b * K;
  const float* Wc = Wt + n;
  float s = 0.f;
#pragma unroll 8
  for (int k = k0; k < k0 + (K >> 4); ++k) {
    float v = row[k];
    if (relu_in) v = fmaxf(v, 0.f);
    s += v * Wc[(size_t)k * N];
  }
  red[w][nl] = s;
  __syncthreads();
  if (w == 0) {
    s = red[0][nl] + red[1][nl] + red[2][nl] + red[3][nl];
    atomicAdd(&out[(size_t)b * N + n], s);
  }
}

extern "C" void kernel_launch(void* const* d_in, const int* in_sizes, int n_in,
                              void* d_out, int out_size, void* d_ws, size_t ws_size,
                              hipStream_t stream) {
  const float* x  = (const float*)d_in[0];
  const float* W  = (const float*)d_in[1];
  const float* V  = (const float*)d_in[2];
  const float* Vb = (const float*)d_in[3];
  const float* W0 = (const float*)d_in[4];
  const float* b0 = (const float*)d_in[5];
  const float* W1 = (const float*)d_in[6];
  const float* b1 = (const float*)d_in[7];
  const float* W2 = (const float*)d_in[8];
  const float* b2 = (const float*)d_in[9];

  char* ws = (char*)d_ws;
  unsigned short* U = (unsigned short*)(ws);                              // 4 MiB
  float* Fagg = (float*)(ws + (size_t)4 * 1024 * 1024);                   // 2 MiB
  float* Zagg = (float*)(ws + (size_t)6 * 1024 * 1024);                   // 2 MiB
  float* h    = (float*)(ws + (size_t)8 * 1024 * 1024);                   // 128 KiB
  float* q0   = (float*)(ws + (size_t)8 * 1024 * 1024 + 256 * 1024);
  float* q1   = (float*)(ws + (size_t)8 * 1024 * 1024 + 512 * 1024);
  uint4* zpg  = (uint4*)(ws + (size_t)12 * 1024 * 1024);                  // 4 KiB zeros
  unsigned short* xb = (unsigned short*)(ws + (size_t)16 * 1024 * 1024);  // 64 MiB

  const size_t need_bf = (size_t)16 * 1024 * 1024 + (size_t)67108864;
  int use_bf = (ws_size >= need_bf) ? 1 : 0;   // constant across calls -> graph-safe

  prologue_kernel<<<8833, 256, 0, stream>>>(x, W, V, b0, b1, b2, xb, U, q0, q1,
                                            (float*)d_out, zpg);
  if (use_bf) {
    qrnn_main4<<<dim3(16, 16, 32), 256, 0, stream>>>((const unsigned short*)ws, Vb, Fagg, Zagg);
  } else {
    qrnn_main<false><<<dim3(16, 16, 32), 256, 0, stream>>>((const unsigned short*)ws, x,
                                                           Vb, Fagg, Zagg);
  }
  head_kernel<<<dim3(16, 32), 256, 0, stream>>>(x, W, V, Vb, Fagg, Zagg, h, 16);
  mlp_atomic_kernel<<<dim3(16, 32, 4), 256, 0, stream>>>(h, W0, q0, 1024, 1024, 0);
  mlp_atomic_kernel<<<dim3(16, 32, 4), 256, 0, stream>>>(q0, W1, q1, 1024, 1024, 1);
  mlp_atomic_kernel<<<dim3(2, 32, 4), 256, 0, stream>>>(q1, W2, (float*)d_out, 1024, 128, 1);
}